// Round 1
// baseline (4820.929 us; speedup 1.0000x reference)
//
#include <hip/hip_runtime.h>
#include <math.h>

// Problem constants (B, L, E, H) = (4, 1024, 2048, 16), DH = 128
#define BB 4
#define LL 1024
#define EE 2048
#define HH 16
#define DHD 128
#define NTOK 4096              // B*L
#define NBH 64                 // B*H
#define OUT0_ELEMS 8388608     // B*L*E
#define ATTN_ELEMS 67108864    // H*B*L*L

// ---------------------------------------------------------------------------
// xPos table: per (t, j) j in [0,64): {cos*scale_q, sin*scale_q, cos*scale_k, sin*scale_k}
// scale_q = base^((t-512)/512), scale_k = 1/scale_q
// ---------------------------------------------------------------------------
__global__ __launch_bounds__(64) void xpos_table_k(float4* __restrict__ tab) {
    int t = blockIdx.x;        // 0..1023
    int j = threadIdx.x;       // 0..63
    float pos = (float)(t - 512);
    float base = (2.0f * (float)j + 51.2f) * (1.0f / 179.2f);
    float sc = powf(base, pos * (1.0f / 512.0f));
    float inv_freq = powf(10000.0f, -(float)j * (1.0f / 64.0f));
    float ang = (float)t * inv_freq;
    float s = sinf(ang);
    float c = cosf(ang);
    tab[(t << 6) | j] = make_float4(c * sc, s * sc, c / sc, s / sc);
}

// ---------------------------------------------------------------------------
// Apply xPos to q (scale) and k (1/scale), in place, split layout (BH, L, DH)
// One thread per (bh, t, j) pair; pair = elements (2j, 2j+1)
// ---------------------------------------------------------------------------
__global__ __launch_bounds__(256) void xpos_apply_k(float* __restrict__ q,
                                                    float* __restrict__ k,
                                                    const float4* __restrict__ tab) {
    int g = blockIdx.x * 256 + threadIdx.x;   // 0 .. 64*1024*64-1
    int j = g & 63;
    int t = (g >> 6) & 1023;
    int bh = g >> 16;
    size_t off = (((size_t)((bh << 10) | t)) << 7) + 2 * j;
    float4 tb = tab[(t << 6) | j];
    float2 qv = *(const float2*)(q + off);
    float2 kv = *(const float2*)(k + off);
    float2 qo, ko;
    qo.x = qv.x * tb.x - qv.y * tb.y;
    qo.y = qv.y * tb.x + qv.x * tb.y;
    ko.x = kv.x * tb.z - kv.y * tb.w;
    ko.y = kv.y * tb.z + kv.x * tb.w;
    *(float2*)(q + off) = qo;
    *(float2*)(k + off) = ko;
}

// ---------------------------------------------------------------------------
// Generic 128x128 tiled fp32 GEMM, BK=16, 256 threads, 8x8 acc per thread.
// MODE 0 (QKV):   C' = alpha*(X @ W^T + bias), write split (BH,L,DH) layout.
//                 A = X (4096x2048), B = W (2048x2048 row = out-feature rows)
// MODE 1 (SCORES): per bh: acc = q[bh] @ k[bh]^T (1024x1024x128);
//                 w = acc + mask[t,s] + rel[bh,t,s]; write d_out attn region
//                 at (h,B,L,L) layout.  bias param = mask, rel param = rel_pos.
// MODE 2 (AV):    per bh: C = P[h,b] @ v[bh]  (1024x128x1024, NN GEMM);
//                 write merged (B,L,E) layout.
// MODE 3 (OUT):   C = A @ Wo^T + bo, plain row-major write (4096x2048).
// ---------------------------------------------------------------------------
template <int MODE>
__global__ __launch_bounds__(256)
void gemm_k(const float* __restrict__ A, const float* __restrict__ Bmat,
            const float* __restrict__ bias, const float* __restrict__ rel,
            float* __restrict__ C, float alpha) {
    __shared__ float smem[4608];                     // 18 KiB
    float (*As)[18]  = (float (*)[18])smem;          // 128 x 18
    float (*Bs)[18]  = (float (*)[18])(smem + 2304); // 128 x 18 (NT modes)
    float (*Bs2)[132] = (float (*)[132])(smem + 2304); // 16 x 132 (NN mode)

    const int tid = threadIdx.x;
    const int tx = tid & 15, ty = tid >> 4;
    const int m0 = blockIdx.y * 128, n0 = blockIdx.x * 128;
    const int bh = blockIdx.z;
    const int hh = bh & 15, bb = bh >> 4;

    constexpr int KDIM = (MODE == 0 || MODE == 3) ? 2048 : (MODE == 1 ? 128 : 1024);
    constexpr int LDA  = (MODE == 0 || MODE == 3) ? 2048 : (MODE == 1 ? 128 : 1024);
    constexpr int LDB  = (MODE == 1) ? 128 : 2048;   // NT modes only

    const float* Ap;
    const float* Bp;
    if constexpr (MODE == 0 || MODE == 3) {
        Ap = A; Bp = Bmat;
    } else if constexpr (MODE == 1) {
        Ap = A + (size_t)bh * LL * DHD;
        Bp = Bmat + (size_t)bh * LL * DHD;
    } else {
        Ap = A + ((size_t)(hh * BB + bb) << 20);     // P page (L*L)
        Bp = Bmat + (size_t)bh * LL * DHD;           // v[bh]
    }

    float acc[8][8];
#pragma unroll
    for (int i = 0; i < 8; ++i)
#pragma unroll
        for (int j = 0; j < 8; ++j) acc[i][j] = 0.0f;

    for (int k0 = 0; k0 < KDIM; k0 += 16) {
#pragma unroll
        for (int u = 0; u < 8; ++u) {
            int idx = u * 256 + tid;
            int r = idx >> 4, c = idx & 15;
            As[r][c] = Ap[(size_t)(m0 + r) * LDA + (k0 + c)];
        }
        if constexpr (MODE != 2) {
#pragma unroll
            for (int u = 0; u < 8; ++u) {
                int idx = u * 256 + tid;
                int r = idx >> 4, c = idx & 15;
                Bs[r][c] = Bp[(size_t)(n0 + r) * LDB + (k0 + c)];
            }
        } else {
#pragma unroll
            for (int u = 0; u < 8; ++u) {
                int idx = u * 256 + tid;
                int r = idx >> 7, c = idx & 127;
                Bs2[r][c] = Bp[(size_t)(k0 + r) * DHD + c];
            }
        }
        __syncthreads();
#pragma unroll
        for (int kk = 0; kk < 16; ++kk) {
            float a[8], b[8];
#pragma unroll
            for (int i = 0; i < 8; ++i) a[i] = As[ty * 8 + i][kk];
            if constexpr (MODE != 2) {
#pragma unroll
                for (int j = 0; j < 8; ++j) b[j] = Bs[tx * 8 + j][kk];
            } else {
#pragma unroll
                for (int j = 0; j < 8; ++j) b[j] = Bs2[kk][tx * 8 + j];
            }
#pragma unroll
            for (int i = 0; i < 8; ++i)
#pragma unroll
                for (int j = 0; j < 8; ++j)
                    acc[i][j] = fmaf(a[i], b[j], acc[i][j]);
        }
        __syncthreads();
    }

    // Epilogue
    if constexpr (MODE == 0) {
#pragma unroll
        for (int i = 0; i < 8; ++i) {
            int m = m0 + ty * 8 + i;
            int b_ = m >> 10, t = m & 1023;
#pragma unroll
            for (int j = 0; j < 8; ++j) {
                int n = n0 + tx * 8 + j;
                int h = n >> 7, d = n & 127;
                size_t dst = (((size_t)((b_ * HH + h)) << 10 | (size_t)t) << 7) | (size_t)d;
                C[dst] = alpha * (acc[i][j] + bias[n]);
            }
        }
    } else if constexpr (MODE == 3) {
#pragma unroll
        for (int i = 0; i < 8; ++i) {
            int m = m0 + ty * 8 + i;
#pragma unroll
            for (int j = 0; j < 8; ++j) {
                int n = n0 + tx * 8 + j;
                C[(size_t)m * EE + n] = acc[i][j] + bias[n];
            }
        }
    } else if constexpr (MODE == 1) {
#pragma unroll
        for (int i = 0; i < 8; ++i) {
            int t = m0 + ty * 8 + i;
#pragma unroll
            for (int j = 0; j < 8; ++j) {
                int s = n0 + tx * 8 + j;
                float w = acc[i][j] + bias[(t << 10) | s]
                          + rel[((size_t)bh << 20) + ((size_t)t << 10) + s];
                C[((size_t)(hh * BB + bb) << 20) + ((size_t)t << 10) + s] = w;
            }
        }
    } else {  // MODE 2: merged (B, L, E) write
#pragma unroll
        for (int i = 0; i < 8; ++i) {
            int m = m0 + ty * 8 + i;
#pragma unroll
            for (int j = 0; j < 8; ++j) {
                int n = n0 + tx * 8 + j;   // n0 == 0 here (N = 128)
                C[(size_t)(bb * LL + m) * EE + hh * DHD + n] = acc[i][j];
            }
        }
    }
}

// ---------------------------------------------------------------------------
// Row softmax in place over last dim (1024), one block per row.
// ---------------------------------------------------------------------------
__global__ __launch_bounds__(256) void softmax_rows_k(float* __restrict__ P) {
    __shared__ float red[8];
    float* row = P + ((size_t)blockIdx.x << 10);
    int tid = threadIdx.x;
    float4 v = *(const float4*)(row + tid * 4);
    float m = fmaxf(fmaxf(v.x, v.y), fmaxf(v.z, v.w));
#pragma unroll
    for (int o = 32; o >= 1; o >>= 1) m = fmaxf(m, __shfl_xor(m, o));
    int wid = tid >> 6, lane = tid & 63;
    if (lane == 0) red[wid] = m;
    __syncthreads();
    m = fmaxf(fmaxf(red[0], red[1]), fmaxf(red[2], red[3]));
    float e0 = expf(v.x - m), e1 = expf(v.y - m), e2 = expf(v.z - m), e3 = expf(v.w - m);
    float s = e0 + e1 + e2 + e3;
#pragma unroll
    for (int o = 32; o >= 1; o >>= 1) s += __shfl_xor(s, o);
    if (lane == 0) red[4 + wid] = s;
    __syncthreads();
    s = red[4] + red[5] + red[6] + red[7];
    float inv = 1.0f / s;
    v.x = e0 * inv; v.y = e1 * inv; v.z = e2 * inv; v.w = e3 * inv;
    *(float4*)(row + tid * 4) = v;
}

// ---------------------------------------------------------------------------
extern "C" void kernel_launch(void* const* d_in, const int* in_sizes, int n_in,
                              void* d_out, int out_size, void* d_ws, size_t ws_size,
                              hipStream_t stream) {
    const float* query = (const float*)d_in[0];
    const float* Wq    = (const float*)d_in[1];
    const float* bq    = (const float*)d_in[2];
    const float* Wk    = (const float*)d_in[3];
    const float* bk    = (const float*)d_in[4];
    const float* Wv    = (const float*)d_in[5];
    const float* bv    = (const float*)d_in[6];
    const float* Wo    = (const float*)d_in[7];
    const float* bo    = (const float*)d_in[8];
    const float* mask  = (const float*)d_in[9];
    const float* rel   = (const float*)d_in[10];

    float* out    = (float*)d_out;              // (B, L, E)
    float* attn_w = out + OUT0_ELEMS;           // (H, B, L, L)

    float* ws = (float*)d_ws;
    float* qs  = ws;                            // (BH, L, DH)
    float* ks  = ws + 1 * OUT0_ELEMS;
    float* vs  = ws + 2 * OUT0_ELEMS;
    float* am  = ws + 3 * OUT0_ELEMS;           // merged (B, L, E)
    float4* tab = (float4*)(ws + 4 * (size_t)OUT0_ELEMS);  // (L, 64) float4

    const float scaling = 0.08838834764831845f; // DH^-0.5

    xpos_table_k<<<LL, 64, 0, stream>>>(tab);

    dim3 gproj(EE / 128, NTOK / 128);           // (16, 32)
    gemm_k<0><<<gproj, 256, 0, stream>>>(query, Wq, bq, nullptr, qs, scaling);
    gemm_k<0><<<gproj, 256, 0, stream>>>(query, Wk, bk, nullptr, ks, 1.0f);
    gemm_k<0><<<gproj, 256, 0, stream>>>(query, Wv, bv, nullptr, vs, 1.0f);

    xpos_apply_k<<<(NBH * LL * 64) / 256, 256, 0, stream>>>(qs, ks, tab);

    dim3 gsc(LL / 128, LL / 128, NBH);          // (8, 8, 64)
    gemm_k<1><<<gsc, 256, 0, stream>>>(qs, ks, mask, rel, attn_w, 1.0f);

    softmax_rows_k<<<NBH * LL, 256, 0, stream>>>(attn_w);

    dim3 gav(1, LL / 128, NBH);                 // (1, 8, 64)
    gemm_k<2><<<gav, 256, 0, stream>>>(attn_w, vs, nullptr, nullptr, am, 1.0f);

    dim3 gout(EE / 128, NTOK / 128);            // (16, 32)
    gemm_k<3><<<gout, 256, 0, stream>>>(am, Wo, bo, nullptr, out, 1.0f);
}

// Round 2
// 780.262 us; speedup vs baseline: 6.1786x; 6.1786x over previous
//
#include <hip/hip_runtime.h>
#include <math.h>

// (B, L, E, H) = (4, 1024, 2048, 16), DH = 128
#define BB 4
#define LL 1024
#define EE 2048
#define HH 16
#define DHD 128
#define NTOK 4096
#define NBH 64
#define OUT0_ELEMS 8388608     // B*L*E

typedef __attribute__((ext_vector_type(8))) short short8;       // 8 bf16 (MFMA A/B frag)
typedef __attribute__((ext_vector_type(4))) float f32x4;        // MFMA C/D frag
typedef __attribute__((ext_vector_type(4))) unsigned short ushort4v;
typedef __attribute__((ext_vector_type(8))) unsigned short ushort8v;

__device__ __forceinline__ unsigned short f2bf(float x) {
    union { float f; unsigned int u; } v; v.f = x;
    unsigned int r = v.u + 0x7FFFu + ((v.u >> 16) & 1u);   // RNE
    return (unsigned short)(r >> 16);
}
__device__ __forceinline__ float bf2f(unsigned short h) {
    union { unsigned int u; float f; } v; v.u = ((unsigned int)h) << 16;
    return v.f;
}

// async global->LDS, 16B per lane; LDS dest = wave-uniform base + lane*16
__device__ __forceinline__ void gload16(const void* g, void* l) {
    __builtin_amdgcn_global_load_lds((const __attribute__((address_space(1))) void*)g,
                                     (__attribute__((address_space(3))) void*)l,
                                     16, 0, 0);
}

// ---------------------------------------------------------------------------
// fp32 -> bf16 bulk convert (8 elems/thread)
// ---------------------------------------------------------------------------
__global__ __launch_bounds__(256) void cvt_k(const float* __restrict__ in,
                                             unsigned short* __restrict__ out, int n) {
    int i = (blockIdx.x * 256 + threadIdx.x) * 8;
    if (i >= n) return;
    float4 a = *(const float4*)(in + i);
    float4 b = *(const float4*)(in + i + 4);
    ushort4v u, w;
    u.x = f2bf(a.x); u.y = f2bf(a.y); u.z = f2bf(a.z); u.w = f2bf(a.w);
    w.x = f2bf(b.x); w.y = f2bf(b.y); w.z = f2bf(b.z); w.w = f2bf(b.w);
    *(ushort4v*)(out + i) = u;
    *(ushort4v*)(out + i + 4) = w;
}

// ---------------------------------------------------------------------------
// xPos table: per (t, j), j in [0,64): {cos*sc, sin*sc, cos/sc, sin/sc}
// ---------------------------------------------------------------------------
__global__ __launch_bounds__(64) void xpos_table_k(float4* __restrict__ tab) {
    int t = blockIdx.x;
    int j = threadIdx.x;
    float pos = (float)(t - 512);
    float base = (2.0f * (float)j + 51.2f) * (1.0f / 179.2f);
    float sc = powf(base, pos * (1.0f / 512.0f));
    float inv_freq = powf(10000.0f, -(float)j * (1.0f / 64.0f));
    float ang = (float)t * inv_freq;
    float s = sinf(ang);
    float c = cosf(ang);
    tab[(t << 6) | j] = make_float4(c * sc, s * sc, c / sc, s / sc);
}

// ---------------------------------------------------------------------------
// xPos rotate q (scale) and k (1/scale) in place, bf16 split layout (BH,L,DH)
// one thread = 8 consecutive d (4 rotation pairs)
// ---------------------------------------------------------------------------
__global__ __launch_bounds__(256) void xpos_apply_k(unsigned short* __restrict__ q,
                                                    unsigned short* __restrict__ k,
                                                    const float4* __restrict__ tab) {
    int g = blockIdx.x * 256 + threadIdx.x;   // 64*1024*16
    int jj = g & 15;
    int t = (g >> 4) & 1023;
    int bh = g >> 14;
    size_t off = (((size_t)((bh << 10) | t)) << 7) + jj * 8;
    ushort8v qv = *(const ushort8v*)(q + off);
    ushort8v kv = *(const ushort8v*)(k + off);
    ushort8v qo, ko;
#pragma unroll
    for (int p = 0; p < 4; ++p) {
        float4 tb = tab[(t << 6) | (jj * 4 + p)];
        float qx = bf2f(qv[2 * p]), qy = bf2f(qv[2 * p + 1]);
        float kx = bf2f(kv[2 * p]), ky = bf2f(kv[2 * p + 1]);
        qo[2 * p]     = f2bf(qx * tb.x - qy * tb.y);
        qo[2 * p + 1] = f2bf(qy * tb.x + qx * tb.y);
        ko[2 * p]     = f2bf(kx * tb.z - ky * tb.w);
        ko[2 * p + 1] = f2bf(ky * tb.z + kx * tb.w);
    }
    *(ushort8v*)(q + off) = qo;
    *(ushort8v*)(k + off) = ko;
}

// ---------------------------------------------------------------------------
// bf16 MFMA GEMM, m97 structure: 128x128 tile, BK=32, 4 waves, 4x4 16x16x32
// frags/wave. A,B both NT (K-contiguous rows).
// MODE 0: Q proj  C=alpha*(X@Wq^T+bq) -> bf16 split (BH,L,DH)
// MODE 1: K proj  -> bf16 split
// MODE 2: V proj  -> bf16 transposed (BH,DH,L)
// MODE 3: scores  per bh: q@k^T + mask + rel -> fp32 attn (H,B,L,L)
// MODE 4: out     C=am@Wo^T+bo -> fp32 (B,L,E)
// MODE 5: AV      per bh: P(fp32, reg-staged->bf16) @ vt^T -> bf16 (B,L,E)
// ---------------------------------------------------------------------------
template <int MODE>
__global__ __launch_bounds__(256)
void mm_k(const void* __restrict__ Aptr, const unsigned short* __restrict__ Bptr,
          const float* __restrict__ bias, const float* __restrict__ rel,
          void* __restrict__ Cptr, float alpha) {
    __shared__ alignas(16) unsigned short lA[128 * 32];
    __shared__ alignas(16) unsigned short lB[128 * 32];

    constexpr int KDIM = (MODE <= 2 || MODE == 4) ? 2048 : (MODE == 3 ? 128 : 1024);
    constexpr int LDA  = (MODE <= 2 || MODE == 4) ? 2048 : (MODE == 3 ? 128 : 1024);
    constexpr int LDB  = (MODE <= 2 || MODE == 4) ? 2048 : (MODE == 3 ? 128 : 1024);

    const int tid = threadIdx.x;
    const int lane = tid & 63;
    const int wave = tid >> 6;
    const int wr = wave >> 1, wc = wave & 1;      // wave sub-tile (64x64)
    const int fr = lane & 15, fq = lane >> 4;
    const int m0 = blockIdx.y * 128, n0 = blockIdx.x * 128;
    const int bh = blockIdx.z;
    const int hh = bh & 15, bb = bh >> 4;

    const unsigned short* Abf = nullptr;
    const float* Af32 = nullptr;
    const unsigned short* Bp;
    if constexpr (MODE <= 2 || MODE == 4) {
        Abf = (const unsigned short*)Aptr;
        Bp  = Bptr;
    } else if constexpr (MODE == 3) {
        Abf = (const unsigned short*)Aptr + (size_t)bh * LL * DHD;
        Bp  = Bptr + (size_t)bh * LL * DHD;
    } else {  // MODE 5
        Af32 = (const float*)Aptr + ((size_t)(hh * BB + bb) << 20);
        Bp   = Bptr + (size_t)bh * DHD * LL;
    }

    f32x4 acc[4][4];
#pragma unroll
    for (int i = 0; i < 4; ++i)
#pragma unroll
        for (int j = 0; j < 4; ++j) acc[i][j] = (f32x4){0.f, 0.f, 0.f, 0.f};

    for (int k0 = 0; k0 < KDIM; k0 += 32) {
        // --- stage A tile (128 x 32 bf16 = 8KB) ---
        if constexpr (MODE != 5) {
#pragma unroll
            for (int i = 0; i < 2; ++i) {
                int c = i * 256 + tid;
                int r = c >> 2, kc = c & 3;
                gload16(Abf + (size_t)(m0 + r) * LDA + k0 + kc * 8, &lA[c * 8]);
            }
        } else {
            // reg-stage fp32 P -> bf16 LDS
#pragma unroll
            for (int i = 0; i < 4; ++i) {
                int c = i * 256 + tid;
                int r = c >> 3, cc = c & 7;
                float4 v = *(const float4*)(Af32 + (size_t)(m0 + r) * 1024 + k0 + cc * 4);
                ushort4v h;
                h.x = f2bf(v.x); h.y = f2bf(v.y); h.z = f2bf(v.z); h.w = f2bf(v.w);
                *(ushort4v*)&lA[r * 32 + cc * 4] = h;
            }
        }
        // --- stage B tile ---
#pragma unroll
        for (int i = 0; i < 2; ++i) {
            int c = i * 256 + tid;
            int r = c >> 2, kc = c & 3;
            gload16(Bp + (size_t)(n0 + r) * LDB + k0 + kc * 8, &lB[c * 8]);
        }
        __syncthreads();

        short8 afr[4], bfr[4];
#pragma unroll
        for (int mi = 0; mi < 4; ++mi)
            afr[mi] = *(const short8*)&lA[(wr * 64 + mi * 16 + fr) * 32 + fq * 8];
#pragma unroll
        for (int ni = 0; ni < 4; ++ni)
            bfr[ni] = *(const short8*)&lB[(wc * 64 + ni * 16 + fr) * 32 + fq * 8];
#pragma unroll
        for (int mi = 0; mi < 4; ++mi)
#pragma unroll
            for (int ni = 0; ni < 4; ++ni)
                acc[mi][ni] = __builtin_amdgcn_mfma_f32_16x16x32_bf16(
                    afr[mi], bfr[ni], acc[mi][ni], 0, 0, 0);
        __syncthreads();
    }

    // --- epilogue: C/D layout row=(lane>>4)*4+reg, col=lane&15 ---
#pragma unroll
    for (int mi = 0; mi < 4; ++mi) {
#pragma unroll
        for (int ni = 0; ni < 4; ++ni) {
#pragma unroll
            for (int r = 0; r < 4; ++r) {
                int m = m0 + wr * 64 + mi * 16 + fq * 4 + r;
                int n = n0 + wc * 64 + ni * 16 + fr;
                float v = acc[mi][ni][r];
                if constexpr (MODE == 0 || MODE == 1) {
                    v = alpha * (v + bias[n]);
                    int b_ = m >> 10, t = m & 1023, h = n >> 7, d = n & 127;
                    unsigned short* q = (unsigned short*)Cptr;
                    q[(((size_t)(b_ * HH + h) << 10 | t) << 7) | d] = f2bf(v);
                } else if constexpr (MODE == 2) {
                    v += bias[n];
                    int b_ = m >> 10, t = m & 1023, h = n >> 7, d = n & 127;
                    unsigned short* vt = (unsigned short*)Cptr;
                    vt[((size_t)(b_ * HH + h) * 128 + d) * 1024 + t] = f2bf(v);
                } else if constexpr (MODE == 3) {
                    float* C = (float*)Cptr;
                    float w = v + bias[(m << 10) | n]
                              + rel[((size_t)bh << 20) | ((size_t)m << 10) | (size_t)n];
                    C[((size_t)(hh * BB + bb) << 20) | ((size_t)m << 10) | (size_t)n] = w;
                } else if constexpr (MODE == 4) {
                    float* C = (float*)Cptr;
                    C[(size_t)m * EE + n] = v + bias[n];
                } else {  // MODE 5
                    unsigned short* am = (unsigned short*)Cptr;
                    am[(size_t)(bb * LL + m) * EE + hh * DHD + n] = f2bf(v);
                }
            }
        }
    }
}

// ---------------------------------------------------------------------------
// Row softmax in place over last dim (1024), fp32, one block per row.
// ---------------------------------------------------------------------------
__global__ __launch_bounds__(256) void softmax_rows_k(float* __restrict__ P) {
    __shared__ float red[8];
    float* row = P + ((size_t)blockIdx.x << 10);
    int tid = threadIdx.x;
    float4 v = *(const float4*)(row + tid * 4);
    float m = fmaxf(fmaxf(v.x, v.y), fmaxf(v.z, v.w));
#pragma unroll
    for (int o = 32; o >= 1; o >>= 1) m = fmaxf(m, __shfl_xor(m, o));
    int wid = tid >> 6, lane = tid & 63;
    if (lane == 0) red[wid] = m;
    __syncthreads();
    m = fmaxf(fmaxf(red[0], red[1]), fmaxf(red[2], red[3]));
    float e0 = expf(v.x - m), e1 = expf(v.y - m), e2 = expf(v.z - m), e3 = expf(v.w - m);
    float s = e0 + e1 + e2 + e3;
#pragma unroll
    for (int o = 32; o >= 1; o >>= 1) s += __shfl_xor(s, o);
    if (lane == 0) red[4 + wid] = s;
    __syncthreads();
    s = red[4] + red[5] + red[6] + red[7];
    float inv = 1.0f / s;
    v.x = e0 * inv; v.y = e1 * inv; v.z = e2 * inv; v.w = e3 * inv;
    *(float4*)(row + tid * 4) = v;
}

// ---------------------------------------------------------------------------
extern "C" void kernel_launch(void* const* d_in, const int* in_sizes, int n_in,
                              void* d_out, int out_size, void* d_ws, size_t ws_size,
                              hipStream_t stream) {
    const float* query = (const float*)d_in[0];
    const float* Wq    = (const float*)d_in[1];
    const float* bq    = (const float*)d_in[2];
    const float* Wk    = (const float*)d_in[3];
    const float* bk    = (const float*)d_in[4];
    const float* Wv    = (const float*)d_in[5];
    const float* bv    = (const float*)d_in[6];
    const float* Wo    = (const float*)d_in[7];
    const float* bo    = (const float*)d_in[8];
    const float* mask  = (const float*)d_in[9];
    const float* rel   = (const float*)d_in[10];

    float* out    = (float*)d_out;              // (B, L, E)
    float* attn_w = out + OUT0_ELEMS;           // (H, B, L, L)

    char* w = (char*)d_ws;
    unsigned short* Xbf = (unsigned short*)(w);               // 16MB  (B*L, E)
    unsigned short* Wqb = (unsigned short*)(w + (16 << 20));  // 8MB
    unsigned short* Wkb = (unsigned short*)(w + (24 << 20));  // 8MB
    unsigned short* Wvb = (unsigned short*)(w + (32 << 20));  // 8MB
    unsigned short* Wob = (unsigned short*)(w + (40 << 20));  // 8MB
    unsigned short* qb  = (unsigned short*)(w + (48 << 20));  // 16MB (BH,L,DH)
    unsigned short* kb  = (unsigned short*)(w + (64 << 20));  // 16MB
    unsigned short* vt  = (unsigned short*)(w + (80 << 20));  // 16MB (BH,DH,L)
    unsigned short* am  = (unsigned short*)(w + (96 << 20));  // 16MB (B,L,E)
    float4* tab         = (float4*)(w + (112 << 20));         // 1MB

    const float scaling = 0.08838834764831845f; // DH^-0.5

    xpos_table_k<<<LL, 64, 0, stream>>>(tab);

    cvt_k<<<4096, 256, 0, stream>>>(query, Xbf, OUT0_ELEMS);
    cvt_k<<<2048, 256, 0, stream>>>(Wq, Wqb, EE * EE);
    cvt_k<<<2048, 256, 0, stream>>>(Wk, Wkb, EE * EE);
    cvt_k<<<2048, 256, 0, stream>>>(Wv, Wvb, EE * EE);
    cvt_k<<<2048, 256, 0, stream>>>(Wo, Wob, EE * EE);

    dim3 gproj(EE / 128, NTOK / 128, 1);        // (16, 32)
    mm_k<0><<<gproj, 256, 0, stream>>>(Xbf, Wqb, bq, nullptr, qb, scaling);
    mm_k<1><<<gproj, 256, 0, stream>>>(Xbf, Wkb, bk, nullptr, kb, 1.0f);
    mm_k<2><<<gproj, 256, 0, stream>>>(Xbf, Wvb, bv, nullptr, vt, 1.0f);

    xpos_apply_k<<<(NBH * LL * 16) / 256, 256, 0, stream>>>(qb, kb, tab);

    dim3 gsc(LL / 128, LL / 128, NBH);          // (8, 8, 64)
    mm_k<3><<<gsc, 256, 0, stream>>>(qb, kb, mask, rel, attn_w, 1.0f);

    softmax_rows_k<<<NBH * LL, 256, 0, stream>>>(attn_w);

    dim3 gav(1, LL / 128, NBH);                 // (1, 8, 64)
    mm_k<5><<<gav, 256, 0, stream>>>(attn_w, vt, nullptr, nullptr, am, 1.0f);

    dim3 gout(EE / 128, NTOK / 128, 1);         // (16, 32)
    mm_k<4><<<gout, 256, 0, stream>>>(am, Wob, bo, nullptr, out, 1.0f);
}